// Round 4
// baseline (801.158 us; speedup 1.0000x reference)
//
#include <hip/hip_runtime.h>
#include <stdint.h>

#define SEQ_LEN 131072
#define IN_DIM  8
#define HID     50
#define NLAYERS 5
#define CHUNK2  256                  // outputs per chain; 2 chains per block
#define WARMUP  768                  // frozen (proven)
#define NBLOCKS 256                  // SEQ_LEN / (2*CHUNK2)
#define RING    64
#define RSH     56                   // halves per ring slot: 112B, 16B-aligned
#define XT      64                   // x-tile steps (double buffered)
#define G       16                   // sync group

typedef float    v4f __attribute__((ext_vector_type(4)));
typedef _Float16 h2  __attribute__((ext_vector_type(2)));
typedef _Float16 h8  __attribute__((ext_vector_type(8)));

#if __has_builtin(__builtin_amdgcn_fdot2)
#define FDOT2(a, b, c) __builtin_amdgcn_fdot2((a), (b), (c), false)
#else
#define FDOT2(a, b, c) __builtin_fmaf((float)(a).x, (float)(b).x, \
                        __builtin_fmaf((float)(a).y, (float)(b).y, (c)))
#endif

__device__ __forceinline__ float fast_tanh(float x) {
    float e = __expf(2.0f * x);
    return 1.0f - 2.0f * __builtin_amdgcn_rcpf(1.0f + e);
}
__device__ __forceinline__ float fast_sigmoid(float x) {
    float e = __expf(-x);
    return __builtin_amdgcn_rcpf(1.0f + e);
}
__device__ __forceinline__ void wait_ge(volatile int* p, int target) {
    while (__hip_atomic_load((int*)p, __ATOMIC_ACQUIRE, __HIP_MEMORY_SCOPE_WORKGROUP) < target) {}
}
// 7 x ds_read_b128 wave-uniform broadcast of one f16 h-row
__device__ __forceinline__ void load7(h8* v, const _Float16* p) {
    const h8* p8 = (const h8*)p;
#pragma unroll
    for (int q = 0; q < 7; q++) v[q] = p8[q];
}
// 50 f32 weights -> 28 h2 (f16), zero-padded
__device__ __forceinline__ void loadw_h(const float* wp, h2* v) {
#pragma unroll
    for (int i = 0; i < 25; i++)
        v[i] = h2{(_Float16)wp[2*i], (_Float16)wp[2*i+1]};
    v[25] = h2{(_Float16)0.f, (_Float16)0.f};
    v[26] = h2{(_Float16)0.f, (_Float16)0.f};
    v[27] = h2{(_Float16)0.f, (_Float16)0.f};
}
// acc += a(56 halves) . w(28 h2), f32 accumulate via v_dot2_f32_f16, 4 chains
__device__ __forceinline__ void dot28(const h8* a, const h2* w,
                                      float& A, float& B, float& C, float& D) {
#pragma unroll
    for (int q = 0; q < 7; q++) {
        A = FDOT2(__builtin_shufflevector(a[q], a[q], 0, 1), w[4*q+0], A);
        B = FDOT2(__builtin_shufflevector(a[q], a[q], 2, 3), w[4*q+1], B);
        C = FDOT2(__builtin_shufflevector(a[q], a[q], 4, 5), w[4*q+2], C);
        D = FDOT2(__builtin_shufflevector(a[q], a[q], 6, 7), w[4*q+3], D);
    }
}

// Layers 1..4, runtime L (ONE instruction stream for 4 waves), TWO chains
// interleaved per step so chain B's independent work hides chain A's
// serial hse-roundtrip/tanh latency.
__device__ void layer2(
    _Float16 (&ring)[2][NLAYERS][RING][RSH], int (&prog)[2][8], const int L,
    const float* __restrict__ WihR, const float* __restrict__ Whh,
    const float* __restrict__ bih,  const float* __restrict__ bhh,
    const int lane, const int win1, const int A0)
{
    const int j = (lane < HID) ? lane : 0;
    h2 winv[28], whhv[28];                       // weights SHARED by both chains
    loadw_h(WihR + (size_t)(L - 1) * HID * HID + j * HID, winv);
    loadw_h(Whh  + (size_t)L * HID * HID + j * HID, whhv);
    const float bias = bih[L * HID + j] + bhh[L * HID + j];

    for (int s = 0; s < win1; s += G) {
        const bool a0 = (s >= A0);               // chain0 active (A0>0 only in blocks 0,1)
        const int  s0 = s - A0;
        wait_ge(&prog[1][L - 1], s + G);
        if (s + G > RING) wait_ge(&prog[1][L + 1], s + G - RING);
        if (a0) {
            wait_ge(&prog[0][L - 1], s0 + G);
            if (s0 + G > RING) wait_ge(&prog[0][L + 1], s0 + G - RING);
        }
        h8 hin1[7], hin0[7];
        load7(hin1, &ring[1][L - 1][s & (RING - 1)][0]);
        if (a0) load7(hin0, &ring[0][L - 1][s0 & (RING - 1)][0]);
#pragma unroll 8
        for (int u = 0; u < G; u++) {
            {   // ---- chain 1 step ----
                const int t = s + u;
                h8 hse[7];
                load7(hse, &ring[1][L][(t - 1) & (RING - 1)][0]);
                float A = bias, B = 0.f, C = 0.f, D = 0.f;
                dot28(hin1, winv, A, B, C, D);
                dot28(hse, whhv, A, B, C, D);
                float h = fast_tanh((A + B) + (C + D));
                if (lane < HID) ring[1][L][t & (RING - 1)][lane] = (_Float16)h;
                if (u < G - 1) load7(hin1, &ring[1][L - 1][(t + 1) & (RING - 1)][0]);
            }
            if (a0) {  // ---- chain 0 step ----
                const int t = s0 + u;
                h8 hse[7];
                load7(hse, &ring[0][L][(t - 1) & (RING - 1)][0]);
                float A = bias, B = 0.f, C = 0.f, D = 0.f;
                dot28(hin0, winv, A, B, C, D);
                dot28(hse, whhv, A, B, C, D);
                float h = fast_tanh((A + B) + (C + D));
                if (lane < HID) ring[0][L][t & (RING - 1)][lane] = (_Float16)h;
                if (u < G - 1) load7(hin0, &ring[0][L - 1][(t + 1) & (RING - 1)][0]);
            }
        }
        if (lane == 0) {
            __hip_atomic_store(&prog[1][L], s + G, __ATOMIC_RELEASE, __HIP_MEMORY_SCOPE_WORKGROUP);
            if (a0)
                __hip_atomic_store(&prog[0][L], s0 + G, __ATOMIC_RELEASE, __HIP_MEMORY_SCOPE_WORKGROUP);
        }
    }
}

extern "C" __global__
__attribute__((amdgpu_flat_work_group_size(384, 384), amdgpu_waves_per_eu(2, 2)))
void rnn_fused(const float* __restrict__ x,     const float* __restrict__ Wih0,
               const float* __restrict__ WihR,  const float* __restrict__ Whh,
               const float* __restrict__ bih,   const float* __restrict__ bhh,
               const float* __restrict__ W1,    const float* __restrict__ b1,
               const float* __restrict__ W2,    const float* __restrict__ b2,
               float* __restrict__ out)
{
    __shared__ __align__(16) float    xsb[2][2 * XT * IN_DIM];      // 8 KB x dbl-buffers
    __shared__ __align__(16) _Float16 ring[2][NLAYERS][RING][RSH];  // 70 KB f16 h rings
    __shared__ int prog[2][8];

    const int c    = blockIdx.x;
    const int tid  = threadIdx.x;
    const int w    = tid >> 6;
    const int lane = tid & 63;

    const int base0 = c * (2 * CHUNK2);
    const int base1 = base0 + CHUNK2;
    const int T00   = (base0 - WARMUP > 0) ? (base0 - WARMUP) : 0;
    const int T01   = (base1 - WARMUP > 0) ? (base1 - WARMUP) : 0;
    const int win0  = base0 + CHUNK2 - T00;     // multiple of G
    const int win1  = base1 + CHUNK2 - T01;     // multiple of G, >= win0
    const int A0    = win1 - win0;              // chain0 activation slot (0 or 256)

    {   // zero ALL ring bytes: h_{-1}=0 AND pads stay 0 forever
        int* rp = (int*)ring;
        const int n = (2 * NLAYERS * RING * RSH * 2) / 4;
        for (int i = tid; i < n; i += 384) rp[i] = 0;
    }
    if (tid < 16) ((int*)prog)[tid] = 0;
    __syncthreads();

    if (w == 0) {
        // ================= layer 0 wave, two chains =================
        const int j = (lane < HID) ? lane : 0;
        v4f winv0, winv1;
        h2  whhv[28];
        winv0 = v4f{Wih0[j*IN_DIM+0], Wih0[j*IN_DIM+1], Wih0[j*IN_DIM+2], Wih0[j*IN_DIM+3]};
        winv1 = v4f{Wih0[j*IN_DIM+4], Wih0[j*IN_DIM+5], Wih0[j*IN_DIM+6], Wih0[j*IN_DIM+7]};
        loadw_h(Whh + j * HID, whhv);
        const float bias = bih[j] + bhh[j];

        const float* xg0 = x + (size_t)T00 * IN_DIM;
        const float* xg1 = x + (size_t)T01 * IN_DIM;
        const int nt0 = win0 >> 6, nt1 = win1 >> 6;
        float4 pf0a, pf0b, pf1a, pf1b;
        {   // prime tile 0 of both chains, register-prefetch tile 1
            const float4* g0 = (const float4*)xg0;
            const float4* g1 = (const float4*)xg1;
            float4* d0 = (float4*)xsb[0];
            float4* d1 = (float4*)xsb[1];
            d0[2*lane] = g0[2*lane]; d0[2*lane+1] = g0[2*lane+1];
            d1[2*lane] = g1[2*lane]; d1[2*lane+1] = g1[2*lane+1];
            const float4* p0 = (const float4*)(xg0 + (size_t)XT * IN_DIM);
            const float4* p1 = (const float4*)(xg1 + (size_t)XT * IN_DIM);
            pf0a = p0[2*lane]; pf0b = p0[2*lane+1];
            pf1a = p1[2*lane]; pf1b = p1[2*lane+1];
        }

        for (int s = 0; s < win1; s += G) {
            const bool a0 = (s >= A0);
            const int  s0 = s - A0;
            if (s + G > RING) wait_ge(&prog[1][1], s + G - RING);
            if (a0 && s0 + G > RING) wait_ge(&prog[0][1], s0 + G - RING);
            if ((s & (XT - 1)) == 0 && s != 0) {       // rotate chain1 x tile
                const int k = s >> 6;
                float4* d = (float4*)xsb[1] + (k & 1) * (XT * IN_DIM / 4);
                d[2*lane] = pf1a; d[2*lane+1] = pf1b;
                if (k + 1 < nt1) {
                    const float4* g = (const float4*)(xg1 + (size_t)(k + 1) * XT * IN_DIM);
                    pf1a = g[2*lane]; pf1b = g[2*lane+1];
                }
            }
            if (a0 && (s0 & (XT - 1)) == 0 && s0 != 0) {  // rotate chain0 x tile
                const int k = s0 >> 6;
                float4* d = (float4*)xsb[0] + (k & 1) * (XT * IN_DIM / 4);
                d[2*lane] = pf0a; d[2*lane+1] = pf0b;
                if (k + 1 < nt0) {
                    const float4* g = (const float4*)(xg0 + (size_t)(k + 1) * XT * IN_DIM);
                    pf0a = g[2*lane]; pf0b = g[2*lane+1];
                }
            }
            v4f xv1[2], xv0[2];
            {
                const v4f* xp = (const v4f*)xsb[1] + ((s >> 6) & 1) * (XT * IN_DIM / 4) + (s & (XT - 1)) * 2;
                xv1[0] = xp[0]; xv1[1] = xp[1];
            }
            if (a0) {
                const v4f* xp = (const v4f*)xsb[0] + ((s0 >> 6) & 1) * (XT * IN_DIM / 4) + (s0 & (XT - 1)) * 2;
                xv0[0] = xp[0]; xv0[1] = xp[1];
            }
#pragma unroll 8
            for (int u = 0; u < G; u++) {
                {   // ---- chain 1 ----
                    const int t = s + u;
                    h8 hse[7];
                    load7(hse, &ring[1][0][(t - 1) & (RING - 1)][0]);
                    float A = bias, B = 0.f, C = 0.f, D = 0.f;
                    A = __builtin_fmaf(xv1[0].x, winv0.x, A);
                    B = __builtin_fmaf(xv1[0].y, winv0.y, B);
                    C = __builtin_fmaf(xv1[0].z, winv0.z, C);
                    D = __builtin_fmaf(xv1[0].w, winv0.w, D);
                    A = __builtin_fmaf(xv1[1].x, winv1.x, A);
                    B = __builtin_fmaf(xv1[1].y, winv1.y, B);
                    C = __builtin_fmaf(xv1[1].z, winv1.z, C);
                    D = __builtin_fmaf(xv1[1].w, winv1.w, D);
                    dot28(hse, whhv, A, B, C, D);
                    float h = fast_tanh((A + B) + (C + D));
                    if (lane < HID) ring[1][0][t & (RING - 1)][lane] = (_Float16)h;
                    if (u < G - 1) {
                        const int t3 = t + 1;
                        const v4f* xp = (const v4f*)xsb[1] + ((t3 >> 6) & 1) * (XT * IN_DIM / 4) + (t3 & (XT - 1)) * 2;
                        xv1[0] = xp[0]; xv1[1] = xp[1];
                    }
                }
                if (a0) {  // ---- chain 0 ----
                    const int t = s0 + u;
                    h8 hse[7];
                    load7(hse, &ring[0][0][(t - 1) & (RING - 1)][0]);
                    float A = bias, B = 0.f, C = 0.f, D = 0.f;
                    A = __builtin_fmaf(xv0[0].x, winv0.x, A);
                    B = __builtin_fmaf(xv0[0].y, winv0.y, B);
                    C = __builtin_fmaf(xv0[0].z, winv0.z, C);
                    D = __builtin_fmaf(xv0[0].w, winv0.w, D);
                    A = __builtin_fmaf(xv0[1].x, winv1.x, A);
                    B = __builtin_fmaf(xv0[1].y, winv1.y, B);
                    C = __builtin_fmaf(xv0[1].z, winv1.z, C);
                    D = __builtin_fmaf(xv0[1].w, winv1.w, D);
                    dot28(hse, whhv, A, B, C, D);
                    float h = fast_tanh((A + B) + (C + D));
                    if (lane < HID) ring[0][0][t & (RING - 1)][lane] = (_Float16)h;
                    if (u < G - 1) {
                        const int t3 = t + 1;
                        const v4f* xp = (const v4f*)xsb[0] + ((t3 >> 6) & 1) * (XT * IN_DIM / 4) + (t3 & (XT - 1)) * 2;
                        xv0[0] = xp[0]; xv0[1] = xp[1];
                    }
                }
            }
            if (lane == 0) {
                __hip_atomic_store(&prog[1][0], s + G, __ATOMIC_RELEASE, __HIP_MEMORY_SCOPE_WORKGROUP);
                if (a0)
                    __hip_atomic_store(&prog[0][0], s0 + G, __ATOMIC_RELEASE, __HIP_MEMORY_SCOPE_WORKGROUP);
            }
        }
    } else if (w <= 4) {
        layer2(ring, prog, w, WihR, Whh, bih, bhh, lane, win1, A0);
    } else {
        // ================= head wave, two chains =================
        const int j = (lane < 20) ? lane : 0;
        h2 w1v[28];
        loadw_h(W1 + j * HID, w1v);
        const float b1_w = b1[j];
        const float w2_w = W2[j];
        const float b2_w = b2[0];

        const int warm0 = win0 - CHUNK2;
        const int warm1 = win1 - CHUNK2;
        if (lane == 0) {   // pre-publish warmup region: layer 4 never stalls there
            __hip_atomic_store(&prog[0][5], warm0, __ATOMIC_RELEASE, __HIP_MEMORY_SCOPE_WORKGROUP);
            __hip_atomic_store(&prog[1][5], warm1, __ATOMIC_RELEASE, __HIP_MEMORY_SCOPE_WORKGROUP);
        }
        // both chains' output windows coincide in global slots [win1-CHUNK2, win1)
        for (int s = win1 - CHUNK2; s < win1; s += G) {
            const int s0 = s - A0;
            wait_ge(&prog[1][4], s + G);
            wait_ge(&prog[0][4], s0 + G);
            h8 h41[7], h40[7];
            load7(h41, &ring[1][4][s & (RING - 1)][0]);
            load7(h40, &ring[0][4][s0 & (RING - 1)][0]);
#pragma unroll 8
            for (int u = 0; u < G; u++) {
                {   // ---- chain 1 ----
                    const int t = T01 + s + u;
                    float A = b1_w, B = 0.f, C = 0.f, D = 0.f;
                    dot28(h41, w1v, A, B, C, D);
                    float z = fmaxf((A + B) + (C + D), 0.f);
                    float zz = (lane < 20) ? z * w2_w : 0.f;
                    if (u < G - 1) load7(h41, &ring[1][4][(s + u + 1) & (RING - 1)][0]);
#pragma unroll
                    for (int off = 32; off > 0; off >>= 1) zz += __shfl_down(zz, off, 64);
                    if (lane == 0) out[t] = fast_sigmoid(zz + b2_w);
                }
                {   // ---- chain 0 ----
                    const int t = T00 + s0 + u;
                    float A = b1_w, B = 0.f, C = 0.f, D = 0.f;
                    dot28(h40, w1v, A, B, C, D);
                    float z = fmaxf((A + B) + (C + D), 0.f);
                    float zz = (lane < 20) ? z * w2_w : 0.f;
                    if (u < G - 1) load7(h40, &ring[0][4][(s0 + u + 1) & (RING - 1)][0]);
#pragma unroll
                    for (int off = 32; off > 0; off >>= 1) zz += __shfl_down(zz, off, 64);
                    if (lane == 0) out[t] = fast_sigmoid(zz + b2_w);
                }
            }
            if (lane == 0) {
                __hip_atomic_store(&prog[1][5], s + G, __ATOMIC_RELEASE, __HIP_MEMORY_SCOPE_WORKGROUP);
                __hip_atomic_store(&prog[0][5], s0 + G, __ATOMIC_RELEASE, __HIP_MEMORY_SCOPE_WORKGROUP);
            }
        }
    }
}

extern "C" void kernel_launch(void* const* d_in, const int* in_sizes, int n_in,
                              void* d_out, int out_size, void* d_ws, size_t ws_size,
                              hipStream_t stream) {
    (void)in_sizes; (void)n_in; (void)d_ws; (void)ws_size; (void)out_size;
    rnn_fused<<<NBLOCKS, 384, 0, stream>>>(
        (const float*)d_in[0], (const float*)d_in[1], (const float*)d_in[2],
        (const float*)d_in[3], (const float*)d_in[4], (const float*)d_in[5],
        (const float*)d_in[6], (const float*)d_in[7], (const float*)d_in[8],
        (const float*)d_in[9], (float*)d_out);
}

// Round 5
// 547.900 us; speedup vs baseline: 1.4622x; 1.4622x over previous
//
#include <hip/hip_runtime.h>
#include <stdint.h>

#define SEQ_LEN 131072
#define IN_DIM  8
#define HID     50
#define NLAYERS 5
#define CHUNK   512                  // outputs per block
#define WARMUP  768                  // frozen (proven)
#define NBLOCKS (SEQ_LEN / CHUNK)    // 256 blocks == 256 CUs
#define RING    64
#define RSH     56                   // halves per ring slot: 112B, 16B-aligned
#define XT      64                   // x-tile steps (double buffered)
#define G       16                   // sync group

typedef float    v4f __attribute__((ext_vector_type(4)));
typedef _Float16 h2  __attribute__((ext_vector_type(2)));
typedef _Float16 h8  __attribute__((ext_vector_type(8)));

#if __has_builtin(__builtin_amdgcn_fdot2)
#define FDOT2(a, b, c) __builtin_amdgcn_fdot2((a), (b), (c), false)
#else
#define FDOT2(a, b, c) __builtin_fmaf((float)(a).x, (float)(b).x, \
                        __builtin_fmaf((float)(a).y, (float)(b).y, (c)))
#endif

__device__ __forceinline__ float fast_tanh(float x) {
    float e = __expf(2.0f * x);
    return 1.0f - 2.0f * __builtin_amdgcn_rcpf(1.0f + e);
}
__device__ __forceinline__ float fast_sigmoid(float x) {
    float e = __expf(-x);
    return __builtin_amdgcn_rcpf(1.0f + e);
}
__device__ __forceinline__ void wait_ge(volatile int* p, int target) {
    while (__hip_atomic_load((int*)p, __ATOMIC_ACQUIRE, __HIP_MEMORY_SCOPE_WORKGROUP) < target) {}
}
// 7 x ds_read_b128 wave-uniform broadcast of one f16 h-row
__device__ __forceinline__ void load7(h8* v, const _Float16* p) {
    const h8* p8 = (const h8*)p;
#pragma unroll
    for (int q = 0; q < 7; q++) v[q] = p8[q];
}
// 50 f32 weights -> 28 h2 (f16), zero-padded
__device__ __forceinline__ void loadw_h(const float* wp, h2* v) {
#pragma unroll
    for (int i = 0; i < 25; i++)
        v[i] = h2{(_Float16)wp[2*i], (_Float16)wp[2*i+1]};
    v[25] = h2{(_Float16)0.f, (_Float16)0.f};
    v[26] = h2{(_Float16)0.f, (_Float16)0.f};
    v[27] = h2{(_Float16)0.f, (_Float16)0.f};
}
// acc += a(56 halves) . w(28 h2), f32 accumulate via v_dot2_f32_f16, 4 chains
__device__ __forceinline__ void dot28(const h8* a, const h2* w,
                                      float& A, float& B, float& C, float& D) {
#pragma unroll
    for (int q = 0; q < 7; q++) {
        A = FDOT2(__builtin_shufflevector(a[q], a[q], 0, 1), w[4*q+0], A);
        B = FDOT2(__builtin_shufflevector(a[q], a[q], 2, 3), w[4*q+1], B);
        C = FDOT2(__builtin_shufflevector(a[q], a[q], 4, 5), w[4*q+2], C);
        D = FDOT2(__builtin_shufflevector(a[q], a[q], 6, 7), w[4*q+3], D);
    }
}

// Software-pipelined layer body: hse(t+1) load is issued right after h(t)'s
// store, then hinAcc(t+1) (independent, data prefetched) is computed INSIDE
// the hse LDS round-trip shadow. Separate accumulators halve the fdot2
// dependency chain (R4 lesson: loads must precede the dependent stretch in
// program order, or the wave blocks at the waitcnt).
template<int L>
__device__ __forceinline__ void layer_lds(
    _Float16 (&ring)[NLAYERS][RING][RSH], int* prog,
    const float* __restrict__ WihR, const float* __restrict__ Whh,
    const float* __restrict__ bih,  const float* __restrict__ bhh,
    int lane, int win)
{
    const int j = (lane < HID) ? lane : 0;
    h2 winv[28], whhv[28];
    loadw_h(WihR + (size_t)(L - 1) * HID * HID + j * HID, winv);
    loadw_h(Whh  + (size_t)L * HID * HID + j * HID, whhv);
    const float bias = bih[L * HID + j] + bhh[L * HID + j];

    for (int s = 0; s < win; s += G) {
        wait_ge(&prog[L - 1], s + G);
        if (s + G > RING) wait_ge(&prog[L + 1], s + G - RING);
        h8 hin[7], hse[7];
        load7(hin, &ring[L - 1][s & (RING - 1)][0]);        // hin(s)
        load7(hse, &ring[L][(s - 1) & (RING - 1)][0]);      // hse(s) in flight
        float A = bias, B = 0.f, C = 0.f, D = 0.f;
        dot28(hin, winv, A, B, C, D);                        // hinAcc(s)
        load7(hin, &ring[L - 1][(s + 1) & (RING - 1)][0]);  // prefetch hin(s+1)
#pragma unroll
        for (int u = 0; u < G; u++) {
            const int t = s + u;
            float e0 = 0.f, e1 = 0.f, e2 = 0.f, e3 = 0.f;
            dot28(hse, whhv, e0, e1, e2, e3);               // waits hse(t)
            float h = fast_tanh(((A + e0) + (B + e1)) + ((C + e2) + (D + e3)));
            if (lane < HID) ring[L][t & (RING - 1)][lane] = (_Float16)h;
            if (u < G - 1) {
                load7(hse, &ring[L][t & (RING - 1)][0]);    // hse(t+1): row just written (LDS in-order)
                A = bias; B = 0.f; C = 0.f; D = 0.f;
                dot28(hin, winv, A, B, C, D);               // hinAcc(t+1) hides hse RT
                if (u < G - 2)
                    load7(hin, &ring[L - 1][(t + 2) & (RING - 1)][0]);  // stays inside waited range
            }
        }
        if (lane == 0)
            __hip_atomic_store(&prog[L], s + G, __ATOMIC_RELEASE, __HIP_MEMORY_SCOPE_WORKGROUP);
    }
}

extern "C" __global__
__attribute__((amdgpu_flat_work_group_size(384, 384), amdgpu_waves_per_eu(2, 2)))
void rnn_fused(const float* __restrict__ x,     const float* __restrict__ Wih0,
               const float* __restrict__ WihR,  const float* __restrict__ Whh,
               const float* __restrict__ bih,   const float* __restrict__ bhh,
               const float* __restrict__ W1,    const float* __restrict__ b1,
               const float* __restrict__ W2,    const float* __restrict__ b2,
               float* __restrict__ out)
{
    __shared__ __align__(16) float    xs[2 * XT * IN_DIM];            // 4 KB x double-buffer
    __shared__ __align__(16) _Float16 ring[NLAYERS][RING][RSH];       // 35 KB f16 h rings
    __shared__ int prog[8];

    const int c    = blockIdx.x;
    const int tid  = threadIdx.x;
    const int w    = tid >> 6;
    const int lane = tid & 63;

    const int t_begin = c * CHUNK;
    const int T0      = (t_begin - WARMUP > 0) ? (t_begin - WARMUP) : 0;
    const int win     = (t_begin + CHUNK) - T0;   // multiple of 64

    {   // zero ALL ring bytes once: h_{-1}=0 AND pad halves stay 0 forever
        int* rp = (int*)ring;
        const int n = (NLAYERS * RING * RSH * 2) / 4;
        for (int i = tid; i < n; i += 384) rp[i] = 0;
    }
    if (tid < 8) prog[tid] = 0;
    __syncthreads();

    if (w == 0) {
        // ================= layer 0 wave (pipelined x-dot) =================
        const int j = (lane < HID) ? lane : 0;
        v4f winv0, winv1;
        h2  whhv[28];
        winv0 = v4f{Wih0[j*IN_DIM+0], Wih0[j*IN_DIM+1], Wih0[j*IN_DIM+2], Wih0[j*IN_DIM+3]};
        winv1 = v4f{Wih0[j*IN_DIM+4], Wih0[j*IN_DIM+5], Wih0[j*IN_DIM+6], Wih0[j*IN_DIM+7]};
        loadw_h(Whh + j * HID, whhv);
        const float bias = bih[j] + bhh[j];

        const float* xg_base = x + (size_t)T0 * IN_DIM;
        const int nt = win >> 6;
        float4 pfa, pfb;
        {   // prime tile 0, register-prefetch tile 1
            const float4* g = (const float4*)xg_base;
            float4 a = g[2 * lane], b = g[2 * lane + 1];
            float4* d = (float4*)xs;
            d[2 * lane] = a; d[2 * lane + 1] = b;
            const float4* g1 = (const float4*)(xg_base + (size_t)XT * IN_DIM);
            pfa = g1[2 * lane]; pfb = g1[2 * lane + 1];
        }

        for (int s = 0; s < win; s += G) {
            if (s + G > RING) wait_ge(&prog[1], s + G - RING);   // consumer freed slots
            if ((s & (XT - 1)) == 0 && s != 0) {                 // rotate x tile
                const int k = s >> 6;
                float4* d = (float4*)xs + (k & 1) * (XT * IN_DIM / 4);
                d[2 * lane] = pfa; d[2 * lane + 1] = pfb;
                if (k + 1 < nt) {
                    const float4* g = (const float4*)(xg_base + (size_t)(k + 1) * XT * IN_DIM);
                    pfa = g[2 * lane]; pfb = g[2 * lane + 1];
                }
            }
            h8 hse[7];
            load7(hse, &ring[0][(s - 1) & (RING - 1)][0]);      // hse(s) in flight
            v4f xn0, xn1;
            float A = bias, B = 0.f, C = 0.f, D = 0.f;
            {   // xAcc(s) + prefetch x(s+1)
                const v4f* xp = (const v4f*)xs + ((s >> 6) & 1) * (XT * IN_DIM / 4) + (s & (XT - 1)) * 2;
                v4f x0 = xp[0], x1 = xp[1];
                A = __builtin_fmaf(x0.x, winv0.x, A);
                B = __builtin_fmaf(x0.y, winv0.y, B);
                C = __builtin_fmaf(x0.z, winv0.z, C);
                D = __builtin_fmaf(x0.w, winv0.w, D);
                A = __builtin_fmaf(x1.x, winv1.x, A);
                B = __builtin_fmaf(x1.y, winv1.y, B);
                C = __builtin_fmaf(x1.z, winv1.z, C);
                D = __builtin_fmaf(x1.w, winv1.w, D);
                const v4f* xq = (const v4f*)xs + (((s + 1) >> 6) & 1) * (XT * IN_DIM / 4) + ((s + 1) & (XT - 1)) * 2;
                xn0 = xq[0]; xn1 = xq[1];
            }
#pragma unroll
            for (int u = 0; u < G; u++) {
                const int t = s + u;
                float e0 = 0.f, e1 = 0.f, e2 = 0.f, e3 = 0.f;
                dot28(hse, whhv, e0, e1, e2, e3);               // waits hse(t)
                float h = fast_tanh(((A + e0) + (B + e1)) + ((C + e2) + (D + e3)));
                if (lane < HID) ring[0][t & (RING - 1)][lane] = (_Float16)h;
                if (u < G - 1) {
                    load7(hse, &ring[0][t & (RING - 1)][0]);    // hse(t+1)
                    A = bias; B = 0.f; C = 0.f; D = 0.f;
                    A = __builtin_fmaf(xn0.x, winv0.x, A);
                    B = __builtin_fmaf(xn0.y, winv0.y, B);
                    C = __builtin_fmaf(xn0.z, winv0.z, C);
                    D = __builtin_fmaf(xn0.w, winv0.w, D);
                    A = __builtin_fmaf(xn1.x, winv1.x, A);
                    B = __builtin_fmaf(xn1.y, winv1.y, B);
                    C = __builtin_fmaf(xn1.z, winv1.z, C);
                    D = __builtin_fmaf(xn1.w, winv1.w, D);
                    if (u < G - 2) {                            // x(t+2): same tile (G | XT)
                        const int t2 = t + 2;
                        const v4f* xq = (const v4f*)xs + ((t2 >> 6) & 1) * (XT * IN_DIM / 4) + (t2 & (XT - 1)) * 2;
                        xn0 = xq[0]; xn1 = xq[1];
                    }
                }
            }
            if (lane == 0)
                __hip_atomic_store(&prog[0], s + G, __ATOMIC_RELEASE, __HIP_MEMORY_SCOPE_WORKGROUP);
        }
    } else if (w == 1) {
        layer_lds<1>(ring, prog, WihR, Whh, bih, bhh, lane, win);
    } else if (w == 2) {
        layer_lds<2>(ring, prog, WihR, Whh, bih, bhh, lane, win);
    } else if (w == 3) {
        layer_lds<3>(ring, prog, WihR, Whh, bih, bhh, lane, win);
    } else if (w == 4) {
        layer_lds<4>(ring, prog, WihR, Whh, bih, bhh, lane, win);
    } else {
        // ================= head wave =================
        const int j = (lane < 20) ? lane : 0;
        h2 w1v[28];
        loadw_h(W1 + j * HID, w1v);
        const float b1_w = b1[j];
        const float w2_w = W2[j];
        const float b2_w = b2[0];

        const int warm = win - CHUNK;
        if (lane == 0)   // pre-publish warmup region: layer 4 never stalls on us there
            __hip_atomic_store(&prog[5], warm, __ATOMIC_RELEASE, __HIP_MEMORY_SCOPE_WORKGROUP);

        for (int s = warm; s < win; s += G) {
            wait_ge(&prog[4], s + G);
            h8 h4[7];
            load7(h4, &ring[4][s & (RING - 1)][0]);
#pragma unroll
            for (int u = 0; u < G; u++) {
                const int s2 = s + u;
                const int t = T0 + s2;
                float A = b1_w, B = 0.f, C = 0.f, D = 0.f;
                dot28(h4, w1v, A, B, C, D);
                float z = (A + B) + (C + D);
                z = fmaxf(z, 0.f);
                float zz = (lane < 20) ? z * w2_w : 0.f;
                if (u < G - 1) load7(h4, &ring[4][(s2 + 1) & (RING - 1)][0]);
#pragma unroll
                for (int off = 32; off > 0; off >>= 1) zz += __shfl_down(zz, off, 64);
                if (lane == 0) out[t] = fast_sigmoid(zz + b2_w);
            }
            if (lane == 0)
                __hip_atomic_store(&prog[5], s + G, __ATOMIC_RELEASE, __HIP_MEMORY_SCOPE_WORKGROUP);
        }
    }
}

extern "C" void kernel_launch(void* const* d_in, const int* in_sizes, int n_in,
                              void* d_out, int out_size, void* d_ws, size_t ws_size,
                              hipStream_t stream) {
    (void)in_sizes; (void)n_in; (void)d_ws; (void)ws_size; (void)out_size;
    rnn_fused<<<NBLOCKS, 384, 0, stream>>>(
        (const float*)d_in[0], (const float*)d_in[1], (const float*)d_in[2],
        (const float*)d_in[3], (const float*)d_in[4], (const float*)d_in[5],
        (const float*)d_in[6], (const float*)d_in[7], (const float*)d_in[8],
        (const float*)d_in[9], (float*)d_out);
}

// Round 6
// 449.245 us; speedup vs baseline: 1.7833x; 1.2196x over previous
//
#include <hip/hip_runtime.h>
#include <stdint.h>

#define SEQ_LEN 131072
#define IN_DIM  8
#define HID     50
#define NLAYERS 5
#define CHUNK   512                  // outputs per block
#define WARMUP  768                  // frozen (proven)
#define NBLOCKS (SEQ_LEN / CHUNK)    // 256 blocks == 256 CUs
#define RING    64
#define RSH     64                   // halves per ring row: 128B; k=50..63 stay ZERO (MFMA K-pad)
#define XT      64                   // x-tile steps (double buffered)
#define G       16                   // sync group == MFMA N dimension

typedef float    v4f   __attribute__((ext_vector_type(4)));
typedef float    f32x4 __attribute__((ext_vector_type(4)));
typedef _Float16 h2    __attribute__((ext_vector_type(2)));
typedef _Float16 h8    __attribute__((ext_vector_type(8)));

#if __has_builtin(__builtin_amdgcn_fdot2)
#define FDOT2(a, b, c) __builtin_amdgcn_fdot2((a), (b), (c), false)
#else
#define FDOT2(a, b, c) __builtin_fmaf((float)(a).x, (float)(b).x, \
                        __builtin_fmaf((float)(a).y, (float)(b).y, (c)))
#endif

__device__ __forceinline__ float fast_tanh(float x) {
    float e = __expf(2.0f * x);
    return 1.0f - 2.0f * __builtin_amdgcn_rcpf(1.0f + e);
}
__device__ __forceinline__ float fast_sigmoid(float x) {
    float e = __expf(-x);
    return __builtin_amdgcn_rcpf(1.0f + e);
}
__device__ __forceinline__ void wait_ge(volatile int* p, int target) {
    while (__hip_atomic_load((int*)p, __ATOMIC_ACQUIRE, __HIP_MEMORY_SCOPE_WORKGROUP) < target) {}
}
// 7 x ds_read_b128 wave-uniform broadcast of one f16 h-row (112B used of 128B)
__device__ __forceinline__ void load7(h8* v, const _Float16* p) {
    const h8* p8 = (const h8*)p;
#pragma unroll
    for (int q = 0; q < 7; q++) v[q] = p8[q];
}
// 50 f32 weights -> 28 h2 (f16), zero-padded
__device__ __forceinline__ void loadw_h(const float* wp, h2* v) {
#pragma unroll
    for (int i = 0; i < 25; i++)
        v[i] = h2{(_Float16)wp[2*i], (_Float16)wp[2*i+1]};
    v[25] = h2{(_Float16)0.f, (_Float16)0.f};
    v[26] = h2{(_Float16)0.f, (_Float16)0.f};
    v[27] = h2{(_Float16)0.f, (_Float16)0.f};
}
// acc += a(56 halves) . w(28 h2), f32 accumulate via v_dot2_f32_f16, 4 chains
__device__ __forceinline__ void dot28(const h8* a, const h2* w,
                                      float& A, float& B, float& C, float& D) {
#pragma unroll
    for (int q = 0; q < 7; q++) {
        A = FDOT2(__builtin_shufflevector(a[q], a[q], 0, 1), w[4*q+0], A);
        B = FDOT2(__builtin_shufflevector(a[q], a[q], 2, 3), w[4*q+1], B);
        C = FDOT2(__builtin_shufflevector(a[q], a[q], 4, 5), w[4*q+2], C);
        D = FDOT2(__builtin_shufflevector(a[q], a[q], 6, 7), w[4*q+3], D);
    }
}

// Layers 1..4 (runtime L: one I-stream for 4 waves).
// hin contribution = bulk GEMM over the 16-step group via MFMA 16x16x32 f16:
//   PRE[j][t] = sum_k Wih[j][k] * hin[k][t]
// B-fragment: lane l holds hin[k=kt*32+(l>>4)*8+i][t=s+(l&15)] — ONE h8
// (non-broadcast b128) per K-tile per group, replacing 112 broadcast b128.
// hse recurrence stays serial in LDS (R3-proven form).
__device__ void layer_mfma(
    _Float16 (&ring)[NLAYERS][RING][RSH],
    float (&pre_lds)[NLAYERS - 1][G][68],
    int* prog, const int L,
    const float* __restrict__ WihR, const float* __restrict__ Whh,
    const float* __restrict__ bih,  const float* __restrict__ bhh,
    const int lane, const int win)
{
    const int j = (lane < HID) ? lane : 0;
    h2 whhv[28];
    loadw_h(Whh + (size_t)L * HID * HID + j * HID, whhv);
    const float bias = bih[L * HID + j] + bhh[L * HID + j];

    // A-fragments: Wih (50x50) as 4 M-tiles x 2 K-tiles, f16.
    // lane l holds A[m*16 + (l&15)][kt*32 + (l>>4)*8 + i], i=0..7
    h8 afr[4][2];
    {
        const float* Wp = WihR + (size_t)(L - 1) * HID * HID;
        const int r0 = lane & 15, kq = (lane >> 4) * 8;
#pragma unroll
        for (int m = 0; m < 4; m++) {
            int row = m * 16 + r0; if (row >= HID) row = 0;   // clamp: rows j>=50 unused
            const float* wr = Wp + row * HID;
#pragma unroll
            for (int kt = 0; kt < 2; kt++) {
                const int k0 = kt * 32 + kq;
#pragma unroll
                for (int i = 0; i < 8; i++)
                    afr[m][kt][i] = (k0 + i < HID) ? (_Float16)wr[k0 + i] : (_Float16)0.f;
            }
        }
    }

    float* prew = &pre_lds[L - 1][0][0];   // [G][68] padded: conflict-light

    for (int s = 0; s < win; s += G) {
        wait_ge(&prog[L - 1], s + G);                        // hin rows s..s+15 ready
        if (s + G > RING) wait_ge(&prog[L + 1], s + G - RING);

        // ---- MFMA phase: PRE[0..63][s..s+15] ----
        {
            const int tr = (s + (lane & 15)) & (RING - 1);
            const int kq = (lane >> 4) * 8;
            h8 b0 = *(const h8*)&ring[L - 1][tr][kq];        // k-tile 0
            h8 b1 = *(const h8*)&ring[L - 1][tr][32 + kq];   // k-tile 1 (k>=50 zeros)
#pragma unroll
            for (int m = 0; m < 4; m++) {
                f32x4 acc = {0.f, 0.f, 0.f, 0.f};
                acc = __builtin_amdgcn_mfma_f32_16x16x32_f16(afr[m][0], b0, acc, 0, 0, 0);
                acc = __builtin_amdgcn_mfma_f32_16x16x32_f16(afr[m][1], b1, acc, 0, 0, 0);
                // D layout: row = m*16+(l>>4)*4+r, col(t) = l&15  -> stage [t][j]
                float* pw = prew + (lane & 15) * 68 + m * 16 + (lane >> 4) * 4;
#pragma unroll
                for (int r = 0; r < 4; r++) pw[r] = acc[r];
            }
        }

        // ---- serial hse phase (R3 shape) ----
#pragma unroll
        for (int u = 0; u < G; u++) {
            const int t = s + u;
            h8 hse[7];
            load7(hse, &ring[L][(t - 1) & (RING - 1)][0]);
            const float pre = prew[u * 68 + lane];           // lane<50 meaningful
            float A = bias + pre, B = 0.f, C = 0.f, D = 0.f;
            dot28(hse, whhv, A, B, C, D);
            float h = fast_tanh((A + B) + (C + D));
            if (lane < HID) ring[L][t & (RING - 1)][lane] = (_Float16)h;
        }
        if (lane == 0)
            __hip_atomic_store(&prog[L], s + G, __ATOMIC_RELEASE, __HIP_MEMORY_SCOPE_WORKGROUP);
    }
}

extern "C" __global__
__attribute__((amdgpu_flat_work_group_size(384, 384), amdgpu_waves_per_eu(2, 2)))
void rnn_fused(const float* __restrict__ x,     const float* __restrict__ Wih0,
               const float* __restrict__ WihR,  const float* __restrict__ Whh,
               const float* __restrict__ bih,   const float* __restrict__ bhh,
               const float* __restrict__ W1,    const float* __restrict__ b1,
               const float* __restrict__ W2,    const float* __restrict__ b2,
               float* __restrict__ out)
{
    __shared__ __align__(16) float    xs[2 * XT * IN_DIM];             // 4 KB
    __shared__ __align__(16) _Float16 ring[NLAYERS][RING][RSH];        // 40 KB
    __shared__ __align__(16) float    pre_lds[NLAYERS - 1][G][68];     // 17 KB
    __shared__ int prog[8];

    const int c    = blockIdx.x;
    const int tid  = threadIdx.x;
    const int w    = tid >> 6;
    const int lane = tid & 63;

    const int t_begin = c * CHUNK;
    const int T0      = (t_begin - WARMUP > 0) ? (t_begin - WARMUP) : 0;
    const int win     = (t_begin + CHUNK) - T0;   // multiple of 64

    {   // zero ALL ring bytes once: h_{-1}=0 AND k>=50 pads stay 0 forever
        int* rp = (int*)ring;
        const int n = (NLAYERS * RING * RSH * 2) / 4;
        for (int i = tid; i < n; i += 384) rp[i] = 0;
    }
    if (tid < 8) prog[tid] = 0;
    __syncthreads();

    if (w == 0) {
        // ================= layer 0 wave (R3-proven form) =================
        const int j = (lane < HID) ? lane : 0;
        v4f winv0, winv1;
        h2  whhv[28];
        winv0 = v4f{Wih0[j*IN_DIM+0], Wih0[j*IN_DIM+1], Wih0[j*IN_DIM+2], Wih0[j*IN_DIM+3]};
        winv1 = v4f{Wih0[j*IN_DIM+4], Wih0[j*IN_DIM+5], Wih0[j*IN_DIM+6], Wih0[j*IN_DIM+7]};
        loadw_h(Whh + j * HID, whhv);
        const float bias = bih[j] + bhh[j];

        const float* xg_base = x + (size_t)T0 * IN_DIM;
        const int nt = win >> 6;
        float4 pfa, pfb;
        {   // prime tile 0, register-prefetch tile 1
            const float4* g = (const float4*)xg_base;
            float4 a = g[2 * lane], b = g[2 * lane + 1];
            float4* d = (float4*)xs;
            d[2 * lane] = a; d[2 * lane + 1] = b;
            const float4* g1 = (const float4*)(xg_base + (size_t)XT * IN_DIM);
            pfa = g1[2 * lane]; pfb = g1[2 * lane + 1];
        }

        for (int s = 0; s < win; s += G) {
            if (s + G > RING) wait_ge(&prog[1], s + G - RING);
            if ((s & (XT - 1)) == 0 && s != 0) {
                const int k = s >> 6;
                float4* d = (float4*)xs + (k & 1) * (XT * IN_DIM / 4);
                d[2 * lane] = pfa; d[2 * lane + 1] = pfb;
                if (k + 1 < nt) {
                    const float4* g = (const float4*)(xg_base + (size_t)(k + 1) * XT * IN_DIM);
                    pfa = g[2 * lane]; pfb = g[2 * lane + 1];
                }
            }
            v4f xv[2];
            {
                const v4f* xp = (const v4f*)xs + ((s >> 6) & 1) * (XT * IN_DIM / 4) + (s & (XT - 1)) * 2;
                xv[0] = xp[0]; xv[1] = xp[1];
            }
#pragma unroll
            for (int u = 0; u < G; u++) {
                const int s2 = s + u;
                h8 hse[7];
                load7(hse, &ring[0][(s2 - 1) & (RING - 1)][0]);
                float A = bias, B = 0.f, C = 0.f, D = 0.f;
                A = __builtin_fmaf(xv[0].x, winv0.x, A);
                B = __builtin_fmaf(xv[0].y, winv0.y, B);
                C = __builtin_fmaf(xv[0].z, winv0.z, C);
                D = __builtin_fmaf(xv[0].w, winv0.w, D);
                A = __builtin_fmaf(xv[1].x, winv1.x, A);
                B = __builtin_fmaf(xv[1].y, winv1.y, B);
                C = __builtin_fmaf(xv[1].z, winv1.z, C);
                D = __builtin_fmaf(xv[1].w, winv1.w, D);
                dot28(hse, whhv, A, B, C, D);
                float h = fast_tanh((A + B) + (C + D));
                if (lane < HID) ring[0][s2 & (RING - 1)][lane] = (_Float16)h;
                if (u < G - 1) {
                    const int s3 = s2 + 1;
                    const v4f* xp = (const v4f*)xs + ((s3 >> 6) & 1) * (XT * IN_DIM / 4) + (s3 & (XT - 1)) * 2;
                    xv[0] = xp[0]; xv[1] = xp[1];
                }
            }
            if (lane == 0)
                __hip_atomic_store(&prog[0], s + G, __ATOMIC_RELEASE, __HIP_MEMORY_SCOPE_WORKGROUP);
        }
    } else if (w <= 4) {
        layer_mfma(ring, pre_lds, prog, w, WihR, Whh, bih, bhh, lane, win);
    } else {
        // ================= head wave (R3-proven form) =================
        const int j = (lane < 20) ? lane : 0;
        h2 w1v[28];
        loadw_h(W1 + j * HID, w1v);
        const float b1_w = b1[j];
        const float w2_w = W2[j];
        const float b2_w = b2[0];

        const int warm = win - CHUNK;
        if (lane == 0)
            __hip_atomic_store(&prog[5], warm, __ATOMIC_RELEASE, __HIP_MEMORY_SCOPE_WORKGROUP);

        for (int s = warm; s < win; s += G) {
            wait_ge(&prog[4], s + G);
            h8 h4[7];
            load7(h4, &ring[4][s & (RING - 1)][0]);
#pragma unroll
            for (int u = 0; u < G; u++) {
                const int s2 = s + u;
                const int t = T0 + s2;
                float A = b1_w, B = 0.f, C = 0.f, D = 0.f;
                dot28(h4, w1v, A, B, C, D);
                float z = (A + B) + (C + D);
                z = fmaxf(z, 0.f);
                float zz = (lane < 20) ? z * w2_w : 0.f;
                if (u < G - 1) load7(h4, &ring[4][(s2 + 1) & (RING - 1)][0]);
#pragma unroll
                for (int off = 32; off > 0; off >>= 1) zz += __shfl_down(zz, off, 64);
                if (lane == 0) out[t] = fast_sigmoid(zz + b2_w);
            }
            if (lane == 0)
                __hip_atomic_store(&prog[5], s + G, __ATOMIC_RELEASE, __HIP_MEMORY_SCOPE_WORKGROUP);
        }
    }
}

extern "C" void kernel_launch(void* const* d_in, const int* in_sizes, int n_in,
                              void* d_out, int out_size, void* d_ws, size_t ws_size,
                              hipStream_t stream) {
    (void)in_sizes; (void)n_in; (void)d_ws; (void)ws_size; (void)out_size;
    rnn_fused<<<NBLOCKS, 384, 0, stream>>>(
        (const float*)d_in[0], (const float*)d_in[1], (const float*)d_in[2],
        (const float*)d_in[3], (const float*)d_in[4], (const float*)d_in[5],
        (const float*)d_in[6], (const float*)d_in[7], (const float*)d_in[8],
        (const float*)d_in[9], (float*)d_out);
}